// Round 2
// baseline (259.613 us; speedup 1.0000x reference)
//
#include <hip/hip_runtime.h>
#include <cstdint>
#include <cstddef>

// Problem dims (fixed by the reference): B=64, S=512, D=768, C=512
#define BB 64
#define SS 512
#define DD 768
#define CC 512

typedef __attribute__((ext_vector_type(8))) short short8;
typedef __attribute__((ext_vector_type(4))) float f32x4;

#define GLOBAL_AS __attribute__((address_space(1)))
#define LDS_AS __attribute__((address_space(3)))

// float -> bf16 bits, round-to-nearest-even
static __device__ __forceinline__ unsigned short f2bf(float f) {
  union { float f; unsigned u; } v; v.f = f;
  unsigned u = v.u;
  u += 0x7FFFu + ((u >> 16) & 1u);
  return (unsigned short)(u >> 16);
}

// async 16B/lane global->LDS copy (wave-uniform LDS base + lane*16)
static __device__ __forceinline__ void async_copy16(const void* g, void* l) {
  __builtin_amdgcn_global_load_lds((const GLOBAL_AS void*)g, (LDS_AS void*)l,
                                   16, 0, 0);
}

// ---------------------------------------------------------------------------
// Kernel 1: normalize label embeddings -> bf16 rows, XOR-swizzled.
// Row c element d is stored at index ((d>>3) ^ (c&7))*8 + (d&7): 16B chunk j
// goes to slot j^(c&7). Keeps the global row contiguous for global_load_lds
// while reducing ds_read_b128 bank aliasing.
// ---------------------------------------------------------------------------
__global__ __launch_bounds__(256) void k_label_norm(const float* __restrict__ L,
                                                    unsigned short* __restrict__ Lnb) {
  const int c = blockIdx.x;
  const int tid = threadIdx.x;
  const float* row = L + (size_t)c * DD;
  float v[3];
  float s = 0.f;
#pragma unroll
  for (int k = 0; k < 3; k++) { v[k] = row[tid + 256 * k]; s += v[k] * v[k]; }
#pragma unroll
  for (int o = 32; o > 0; o >>= 1) s += __shfl_xor(s, o, 64);
  __shared__ float wsum[4];
  if ((tid & 63) == 0) wsum[tid >> 6] = s;
  __syncthreads();
  const float tot = wsum[0] + wsum[1] + wsum[2] + wsum[3];
  const float inv = 1.f / fmaxf(sqrtf(tot), 1e-8f);
  unsigned short* orow = Lnb + (size_t)c * DD;
  const int sw = c & 7;
#pragma unroll
  for (int k = 0; k < 3; k++) {
    const int d = tid + 256 * k;
    const int idx = (((d >> 3) ^ sw) << 3) | (d & 7);
    orow[idx] = f2bf(v[k] * inv);
  }
}

// ---------------------------------------------------------------------------
// Kernel 2: m[b,s] = max_c dot(V[b,s,:], Ln[c,:]) / max(||V||,eps)
// 512 blocks x 2 waves x 32 tokens/wave. Each wave holds TWO 16-token A
// fragment groups in registers (48 x short8 = 192 VGPR) so every B ds_read
// feeds 2 MFMAs (halved LDS traffic vs 16 tokens/wave). Accumulation is
// split into 8 independent chains (4 per token group) to hide MFMA
// dependent latency; chains are summed elementwise before the class-max.
// Double-buffered async global_load_lds staging as before (prefetch at top
// of iteration, drained by the __syncthreads at the bottom -> covered by
// the MFMA/LDS compute phase).
// ---------------------------------------------------------------------------
__global__ __launch_bounds__(128, 1) void k_sims_max(const float* __restrict__ V,
                                                     const unsigned short* __restrict__ Lnb,
                                                     float* __restrict__ m_out) {
  const int tid = threadIdx.x;
  const int wave = tid >> 6;   // 0..1
  const int lane = tid & 63;
  const int q = lane >> 4;     // quad 0..3 (k-subgroup for A/B, row-group for D)
  const int mr = lane & 15;    // row (token) for A, col (class) for B/D
  const int64_t tokBase = (int64_t)blockIdx.x * 64 + wave * 32;

  __shared__ unsigned short Bs[2][16 * DD];  // 2 x 24576 B
  __shared__ float nrmS[2][32];

  // ---- prefetch class-chunk 0 into buf 0 (async, in flight during A load)
  {
    const char* src = (const char*)Lnb;
    char* dst = (char*)&Bs[0][0];
#pragma unroll
    for (int i = wave; i < 24; i += 2)
      async_copy16(src + i * 1024 + lane * 16, dst + i * 1024);
  }

  // ---- load A fragments (two 16-token groups) + squared norms
  const float* arow0 = V + (tokBase + mr) * DD + q * 8;
  const float* arow1 = arow0 + 16 * DD;
  short8 a0[24], a1[24];
  float n0 = 0.f, n1 = 0.f;
#pragma unroll
  for (int kc = 0; kc < 24; kc++) {
    const float4* p0 = (const float4*)(arow0 + kc * 32);
    float4 x = p0[0];
    float4 y = p0[1];
    short8 a;
    a[0] = (short)f2bf(x.x); a[1] = (short)f2bf(x.y);
    a[2] = (short)f2bf(x.z); a[3] = (short)f2bf(x.w);
    a[4] = (short)f2bf(y.x); a[5] = (short)f2bf(y.y);
    a[6] = (short)f2bf(y.z); a[7] = (short)f2bf(y.w);
    a0[kc] = a;
    n0 += x.x * x.x + x.y * x.y + x.z * x.z + x.w * x.w;
    n0 += y.x * y.x + y.y * y.y + y.z * y.z + y.w * y.w;
    const float4* p1 = (const float4*)(arow1 + kc * 32);
    x = p1[0];
    y = p1[1];
    short8 c;
    c[0] = (short)f2bf(x.x); c[1] = (short)f2bf(x.y);
    c[2] = (short)f2bf(x.z); c[3] = (short)f2bf(x.w);
    c[4] = (short)f2bf(y.x); c[5] = (short)f2bf(y.y);
    c[6] = (short)f2bf(y.z); c[7] = (short)f2bf(y.w);
    a1[kc] = c;
    n1 += x.x * x.x + x.y * x.y + x.z * x.z + x.w * x.w;
    n1 += y.x * y.x + y.y * y.y + y.z * y.z + y.w * y.w;
  }
  // lanes {m, m+16, m+32, m+48} each hold 1/4 of the token's sum of squares
  n0 += __shfl_xor(n0, 16, 64);
  n0 += __shfl_xor(n0, 32, 64);
  n1 += __shfl_xor(n1, 16, 64);
  n1 += __shfl_xor(n1, 32, 64);
  if (q == 0) { nrmS[wave][mr] = n0; nrmS[wave][16 + mr] = n1; }

  __syncthreads();  // buf0 staged (vmcnt drain)

  const int sw = mr & 7;  // ds_read swizzle key (row = class index mod 8)
  f32x4 vmax0 = {-3e38f, -3e38f, -3e38f, -3e38f};
  f32x4 vmax1 = {-3e38f, -3e38f, -3e38f, -3e38f};
  for (int cc = 0; cc < 32; cc++) {
    const int p = cc & 1;
    // prefetch next chunk into the other buffer (its readers finished at the
    // barrier ending iteration cc-1)
    if (cc + 1 < 32) {
      const char* src = (const char*)(Lnb + (size_t)(cc + 1) * 16 * DD);
      char* dst = (char*)&Bs[p ^ 1][0];
#pragma unroll
      for (int i = wave; i < 24; i += 2)
        async_copy16(src + i * 1024 + lane * 16, dst + i * 1024);
    }
    // 8 independent accumulator chains (4 per token group, depth 6 each)
    f32x4 acc0[4], acc1[4];
#pragma unroll
    for (int j = 0; j < 4; j++) {
      acc0[j] = (f32x4){0.f, 0.f, 0.f, 0.f};
      acc1[j] = (f32x4){0.f, 0.f, 0.f, 0.f};
    }
#pragma unroll
    for (int kc = 0; kc < 24; kc++) {
      // chunk (kc*4+q) of class-row mr lives at slot (kc*4+q)^(mr&7)
      const int off = mr * DD + ((((kc << 2) + q) ^ sw) << 3);
      const short8 b = *(const short8*)&Bs[p][off];
      acc0[kc & 3] = __builtin_amdgcn_mfma_f32_16x16x32_bf16(a0[kc], b, acc0[kc & 3], 0, 0, 0);
      acc1[kc & 3] = __builtin_amdgcn_mfma_f32_16x16x32_bf16(a1[kc], b, acc1[kc & 3], 0, 0, 0);
    }
    const f32x4 s0 = (acc0[0] + acc0[1]) + (acc0[2] + acc0[3]);
    const f32x4 s1 = (acc1[0] + acc1[1]) + (acc1[2] + acc1[3]);
    vmax0[0] = fmaxf(vmax0[0], s0[0]); vmax0[1] = fmaxf(vmax0[1], s0[1]);
    vmax0[2] = fmaxf(vmax0[2], s0[2]); vmax0[3] = fmaxf(vmax0[3], s0[3]);
    vmax1[0] = fmaxf(vmax1[0], s1[0]); vmax1[1] = fmaxf(vmax1[1], s1[1]);
    vmax1[2] = fmaxf(vmax1[2], s1[2]); vmax1[3] = fmaxf(vmax1[3], s1[3]);
    __syncthreads();  // drains prefetch vmcnt + guards buffer reuse
  }
  // reduce max over the 16 column-lanes (classes) of each quad
#pragma unroll
  for (int o = 1; o < 16; o <<= 1) {
#pragma unroll
    for (int r = 0; r < 4; r++) {
      vmax0[r] = fmaxf(vmax0[r], __shfl_xor(vmax0[r], o, 64));
      vmax1[r] = fmaxf(vmax1[r], __shfl_xor(vmax1[r], o, 64));
    }
  }
  // D rows held by this quad are tokens q*4 + r (per 16-token group)
  if (mr == 0) {
#pragma unroll
    for (int r = 0; r < 4; r++) {
      const float d0 = nrmS[wave][q * 4 + r];
      const float d1 = nrmS[wave][16 + q * 4 + r];
      m_out[tokBase + q * 4 + r] = vmax0[r] / fmaxf(sqrtf(d0), 1e-8f);
      m_out[tokBase + 16 + q * 4 + r] = vmax1[r] / fmaxf(sqrtf(d1), 1e-8f);
    }
  }
}

// ---------------------------------------------------------------------------
// Kernel 3: fused softmax + partial z over (batch, s-chunk).
// grid = B*nsc x 192 threads. Each block recomputes the batch's softmax
// stats from m (512 floats, L2-hit, ~2 cheap block reductions), then
// accumulates acc = sum_s exp(m_s - mx) * V[s], scaling by 1/sum at the end.
// Second (and last) full read of V, coalesced; beta never materialized.
// ---------------------------------------------------------------------------
__global__ __launch_bounds__(192) void k_zpart(const float* __restrict__ V,
                                               const float* __restrict__ m,
                                               float* __restrict__ zpart,
                                               int spc, int nsc) {
  const int blk = blockIdx.x;
  const int b = blk / nsc;
  const int sc = blk % nsc;
  const int tid = threadIdx.x;
  const float* mb = m + (size_t)b * SS;

  // ---- softmax stats over the 512 m-values of batch b
  const float x0 = mb[tid];
  const float x1 = mb[tid + 192];
  const float x2 = (tid < 128) ? mb[tid + 384] : -3e38f;
  float mx = fmaxf(fmaxf(x0, x1), x2);
#pragma unroll
  for (int o = 32; o > 0; o >>= 1) mx = fmaxf(mx, __shfl_xor(mx, o, 64));
  __shared__ float redm[3];
  __shared__ float reds[3];
  if ((tid & 63) == 0) redm[tid >> 6] = mx;
  __syncthreads();
  mx = fmaxf(redm[0], fmaxf(redm[1], redm[2]));
  float es = __expf(x0 - mx) + __expf(x1 - mx) +
             ((tid < 128) ? __expf(x2 - mx) : 0.f);
#pragma unroll
  for (int o = 32; o > 0; o >>= 1) es += __shfl_xor(es, o, 64);
  if ((tid & 63) == 0) reds[tid >> 6] = es;
  __syncthreads();
  const float inv = 1.f / (reds[0] + reds[1] + reds[2]);

  // ---- weighted partial sum over this block's s-chunk
  const float* vb = V + ((size_t)b * SS + (size_t)sc * spc) * DD + tid * 4;
  const float* msc = mb + (size_t)sc * spc;
  float4 acc = {0.f, 0.f, 0.f, 0.f};
#pragma unroll 4
  for (int s = 0; s < spc; s++) {
    const float w = __expf(msc[s] - mx);
    const float4 x = *(const float4*)(vb + (size_t)s * DD);
    acc.x += w * x.x; acc.y += w * x.y; acc.z += w * x.z; acc.w += w * x.w;
  }
  acc.x *= inv; acc.y *= inv; acc.z *= inv; acc.w *= inv;
  *(float4*)(zpart + (size_t)blk * DD + tid * 4) = acc;
}

// ---------------------------------------------------------------------------
// Kernel 4: reduce z-partials -> z (to out), then out = z @ fc_w^T + fc_b.
// grid = 2*B blocks (b, class-half) x 256 threads; fc_w L2/L3-resident.
// ---------------------------------------------------------------------------
__global__ __launch_bounds__(256) void k_final(const float* __restrict__ zpart,
                                               const float* __restrict__ fc_w,
                                               const float* __restrict__ fc_b,
                                               float* __restrict__ out,
                                               float* __restrict__ zout,
                                               int nsc) {
  const int b = blockIdx.x >> 1;
  const int half = blockIdx.x & 1;
  const int tid = threadIdx.x;
  __shared__ float zs[DD];
  for (int i = tid; i < DD; i += 256) {
    float s = 0.f;
    for (int sc = 0; sc < nsc; sc++) s += zpart[((size_t)b * nsc + sc) * DD + i];
    zs[i] = s;
    if (half == 0) zout[(size_t)b * DD + i] = s;
  }
  __syncthreads();
  const int c = half * 256 + tid;
  const float4* w = (const float4*)(fc_w + (size_t)c * DD);
  float acc = 0.f;
  for (int d4 = 0; d4 < DD / 4; d4++) {
    const float4 ww = w[d4];
    acc += ww.x * zs[d4 * 4] + ww.y * zs[d4 * 4 + 1] +
           ww.z * zs[d4 * 4 + 2] + ww.w * zs[d4 * 4 + 3];
  }
  out[(size_t)b * CC + c] = acc + fc_b[c];
}

// ---------------------------------------------------------------------------
extern "C" void kernel_launch(void* const* d_in, const int* in_sizes, int n_in,
                              void* d_out, int out_size, void* d_ws, size_t ws_size,
                              hipStream_t stream) {
  const float* V  = (const float*)d_in[0];  // [64,512,768]
  const float* L  = (const float*)d_in[1];  // [512,768]
  const float* fw = (const float*)d_in[2];  // [512,768]
  const float* fb = (const float*)d_in[3];  // [512]
  float* out = (float*)d_out;               // [64*512] out, then [64*768] z

  char* ws = (char*)d_ws;
  unsigned short* Lnb = (unsigned short*)ws;            // 786432 B (swizzled)
  float* m     = (float*)(ws + 786432);                 // 131072 B
  float* zpart = (float*)(ws + 917504);                 // nsc*64*768*4 B

  // 16 s-chunks if the workspace allows, else 8
  const int nsc = (ws_size >= (size_t)917504 + (size_t)16 * BB * DD * 4) ? 16 : 8;
  const int spc = SS / nsc;

  k_label_norm<<<CC, 256, 0, stream>>>(L, Lnb);
  k_sims_max<<<512, 128, 0, stream>>>(V, Lnb, m);
  k_zpart<<<BB * nsc, 192, 0, stream>>>(V, m, zpart, spc, nsc);
  k_final<<<2 * BB, 256, 0, stream>>>(zpart, fw, fb, out, out + BB * CC, nsc);
}